// Round 10
// baseline (987.747 us; speedup 1.0000x reference)
//
#include <hip/hip_runtime.h>

typedef unsigned short u16;   // raw bf16 bits (INTERNAL storage only)
typedef __attribute__((ext_vector_type(4))) float f32x4;
typedef __attribute__((ext_vector_type(2))) float f32x2;
typedef __attribute__((ext_vector_type(8))) short bf16x8;

constexpr int Nn  = 50000;
constexpr int Ee  = 500000;
constexpr int ET  = Nn + Ee;      // edges incl. self-loops
constexpr int FIN = 128;
constexpr int FE  = 16;
constexpr int Hh  = 8;
constexpr int C1  = 32, HC1 = 256;
constexpr int C2  = 16, HC2 = 128;
constexpr float NS  = 0.2f;
constexpr float EPS = 1e-5f;
constexpr int BNB = 256;          // bn partial blocks

__device__ __forceinline__ float b2f(u16 u) { return __uint_as_float(((unsigned)u) << 16); }
__device__ __forceinline__ u16 f2b(float f) {
  unsigned u = __float_as_uint(f);
  u += 0x7FFF + ((u >> 16) & 1);          // round-to-nearest-even
  return (u16)(u >> 16);
}
__device__ __forceinline__ f32x2 ldbf2(const u16* p) {
  ushort2 u = *reinterpret_cast<const ushort2*>(p);
  return (f32x2){b2f(u.x), b2f(u.y)};
}
__device__ __forceinline__ void stbf2(u16* p, f32x2 v) {
  ushort2 u; u.x = f2b(v.x); u.y = f2b(v.y);
  *reinterpret_cast<ushort2*>(p) = u;
}

// ---------------- edge_attr mean (for self-loop fill) ----------------
__global__ void k_ea_mean(const float* __restrict__ ea, float* __restrict__ ea_mean) {
  __shared__ float s[256];
  int f  = threadIdx.x & 15;
  int r0 = (threadIdx.x >> 4) + blockIdx.x * 16;
  float acc = 0.f;
  for (int e = r0; e < Ee; e += gridDim.x * 16) acc += ea[e * FE + f];
  s[threadIdx.x] = acc;
  __syncthreads();
  if (threadIdx.x < 16) {
    float t = 0.f;
    for (int r = 0; r < 16; r++) t += s[r * 16 + threadIdx.x];
    atomicAdd(&ea_mean[threadIdx.x], t * (1.f / Ee));
  }
}

// ---------------- CSR build (by destination) ----------------
__global__ void k_deg(const int* __restrict__ ei, int* __restrict__ deg) {
  int e = blockIdx.x * 256 + threadIdx.x;
  if (e >= ET) return;
  int d = (e < Ee) ? ei[Ee + e] : (e - Ee);
  if ((unsigned)d >= (unsigned)Nn) d = 0;   // safety clamp
  atomicAdd(&deg[d], 1);
}

__global__ __launch_bounds__(1024) void k_scan(const int* __restrict__ deg, int* __restrict__ rowptr) {
  const int T = 1024;
  int t = threadIdx.x;
  const int CH = (Nn + T - 1) / T;  // 49
  int base = t * CH;
  int sum = 0;
  for (int i = 0; i < CH; i++) {
    int idx = base + i;
    if (idx < Nn) sum += deg[idx];
  }
  __shared__ int s[T];
  s[t] = sum;
  __syncthreads();
  for (int off = 1; off < T; off <<= 1) {
    int v = (t >= off) ? s[t - off] : 0;
    __syncthreads();
    s[t] += v;
    __syncthreads();
  }
  int run = (t == 0) ? 0 : s[t - 1];
  for (int i = 0; i < CH; i++) {
    int idx = base + i;
    if (idx < Nn) { rowptr[idx] = run; run += deg[idx]; }
  }
  if (t == T - 1) rowptr[Nn] = run;  // == ET
}

__global__ void k_scatter(const int* __restrict__ ei, const int* __restrict__ rowptr,
                          int* __restrict__ cursor, int2* __restrict__ epack) {
  int e = blockIdx.x * 256 + threadIdx.x;
  if (e >= ET) return;
  int s, d;
  if (e < Ee) { s = ei[e]; d = ei[Ee + e]; } else { s = d = e - Ee; }
  if ((unsigned)s >= (unsigned)Nn) s = 0;   // safety clamp
  if ((unsigned)d >= (unsigned)Nn) d = 0;
  int pos = rowptr[d] + atomicAdd(&cursor[d], 1);
  epack[pos] = make_int2(s, e);
}

// ---------------- BN: per-block partial sums (no atomics, no memset) ----------------
template <int HC>
__global__ void k_bn_stats(const u16* __restrict__ x, float* __restrict__ psum, float* __restrict__ psq) {
  int b = blockIdx.x, tid = threadIdx.x;
  long e0 = (long)b * 256 + tid;
  long stride = (long)BNB * 256;
  float s = 0.f, s2 = 0.f;
  for (long e = e0; e < (long)Nn * HC; e += stride) {
    float v = b2f(x[e]);
    s += v; s2 += v * v;
  }
  psum[b * 256 + tid] = s;
  psq[b * 256 + tid] = s2;
}

__global__ void k_bn_coef(const float* __restrict__ psum, const float* __restrict__ psq,
                          const float* __restrict__ g, const float* __restrict__ bt,
                          float2* __restrict__ coef, int HC) {
  int ch = threadIdx.x;
  if (ch >= HC) return;
  float s = 0.f, s2 = 0.f;
  for (int b = 0; b < BNB; b++)
    for (int r = ch; r < 256; r += HC) { s += psum[b * 256 + r]; s2 += psq[b * 256 + r]; }
  float mu = s * (1.f / Nn);
  float var = s2 * (1.f / Nn) - mu * mu;
  float rs = rsqrtf(var + EPS);
  float sc = g[ch] * rs;
  coef[ch] = make_float2(sc, bt[ch] - sc * mu);
}

// ------- MFMA bf16 GEMM: C[M,NN] = act(A)[M,KK] @ W[KK,NN] + bias; C stored bf16 -------
template <int KK, int NN, typename AT, bool FUSE>
__global__ __launch_bounds__(256) void k_gemm_mfma(const AT* __restrict__ A, const float* __restrict__ W,
                                                   const float* __restrict__ bias, u16* __restrict__ C,
                                                   const float2* __restrict__ coef, int M) {
  constexpr int WT = KK + 8;
  __shared__ u16 Wt[64 * WT];
  int tid = threadIdx.x;
  int col0 = blockIdx.x * 64;
  int row0 = blockIdx.y * 64;
  for (int idx = tid; idx < KK * 64; idx += 256) {   // stage W -> LDS (transposed, bf16)
    int k = idx >> 6, c = idx & 63;
    Wt[c * WT + k] = f2b(W[(size_t)k * NN + col0 + c]);
  }
  __syncthreads();
  int lane = tid & 63;
  int w = tid >> 6;
  int mr = lane & 15, quad = lane >> 4;
  int row = row0 + w * 16 + mr;
  f32x4 acc[4];
#pragma unroll
  for (int t = 0; t < 4; t++) acc[t] = (f32x4){0.f, 0.f, 0.f, 0.f};
  union Frag { bf16x8 v; u16 u[8]; };
  for (int kb = 0; kb < KK; kb += 32) {
    Frag a;
    if (row < M) {
      if constexpr (sizeof(AT) == 4) {               // fp32 input -> convert
        const float* ap = (const float*)&A[(size_t)row * KK + kb + quad * 8];
        float4 a0 = *reinterpret_cast<const float4*>(ap);
        float4 a1 = *reinterpret_cast<const float4*>(ap + 4);
        a.u[0] = f2b(a0.x); a.u[1] = f2b(a0.y); a.u[2] = f2b(a0.z); a.u[3] = f2b(a0.w);
        a.u[4] = f2b(a1.x); a.u[5] = f2b(a1.y); a.u[6] = f2b(a1.z); a.u[7] = f2b(a1.w);
      } else {                                       // bf16 internal
        a.v = *reinterpret_cast<const bf16x8*>(&A[(size_t)row * KK + kb + quad * 8]);
        if constexpr (FUSE) {
          int k0 = kb + quad * 8;
#pragma unroll
          for (int j = 0; j < 8; j++) {
            float2 c2 = coef[k0 + j];
            float y = b2f(a.u[j]) * c2.x + c2.y;
            y = y > 0.f ? y : __expf(y) - 1.f;       // ELU
            a.u[j] = f2b(y);
          }
        }
      }
    } else {
#pragma unroll
      for (int j = 0; j < 8; j++) a.u[j] = 0;
    }
#pragma unroll
    for (int t = 0; t < 4; t++) {
      const bf16x8* bp = reinterpret_cast<const bf16x8*>(&Wt[(t * 16 + mr) * WT + kb + quad * 8]);
      acc[t] = __builtin_amdgcn_mfma_f32_16x16x32_bf16(a.v, *bp, acc[t], 0, 0, 0);
    }
  }
  int orow = row0 + w * 16 + quad * 4;
#pragma unroll
  for (int t = 0; t < 4; t++) {
    int col = col0 + t * 16 + mr;
    float bs = bias[col];
#pragma unroll
    for (int r = 0; r < 4; r++) {
      int rr = orow + r;
      if (rr < M) C[(size_t)rr * NN + col] = f2b(acc[t][r] + bs);
    }
  }
}

// ---- fused GATv2 attention: logits + online softmax + aggregation ----
// 8-deep masked batches: clamp invalid slots to last edge, weight them 0 via part=-1e30.
template <int HC, int C, int WPN>
__global__ __launch_bounds__(256) void k_node_attn(
    const int* __restrict__ rowptr, const int2* __restrict__ epack,
    const u16* __restrict__ xl, const float* __restrict__ We, const float* __restrict__ att,
    const float* __restrict__ edge_attr, const float* __restrict__ ea_mean,
    const float* __restrict__ bo, u16* __restrict__ out) {
  int lane = threadIdx.x & 63;
  int gwid = (blockIdx.x << 2) + (threadIdx.x >> 6);
  int nwaves = gridDim.x << 2;          // multiple of WPN by launch config
  int w = gwid % WPN;
  int i0 = gwid / WPN;
  int istride = nwaves / WPN;
  int c0 = w * 128 + lane * 2;
  f32x2 w2[FE];
#pragma unroll
  for (int k = 0; k < FE; k++) {
    float2 t = *reinterpret_cast<const float2*>(&We[k * HC + c0]);
    w2[k] = (f32x2){t.x, t.y};
  }
  float at0 = att[c0], at1 = att[c0 + 1];
  f32x2 ews2 = {0.f, 0.f};
#pragma unroll
  for (int k = 0; k < FE; k++) ews2 += ea_mean[k] * w2[k];
  float b0 = bo[c0], b1 = bo[c0 + 1];
  constexpr int RED = C / 2;                       // lanes per head
  constexpr int UN = 8;

  auto edge_ew = [&](int eid) -> f32x2 {
    if (eid < Ee) {                                // scalar (uniform) branch
      const float4* ep = reinterpret_cast<const float4*>(&edge_attr[(size_t)eid * FE]);
      f32x2 a = {0.f, 0.f};
#pragma unroll
      for (int k4 = 0; k4 < 4; k4++) {
        float4 u = ep[k4];
        a += u.x * w2[4 * k4 + 0];
        a += u.y * w2[4 * k4 + 1];
        a += u.z * w2[4 * k4 + 2];
        a += u.w * w2[4 * k4 + 3];
      }
      return a;
    }
    return ews2;
  };

  for (int i = i0; i < Nn; i += istride) {
    int p0 = rowptr[i], p1 = rowptr[i + 1];      // p1 > p0 (self-loop guarantees deg>=1)
    f32x2 xd = ldbf2(&xl[(size_t)i * HC + c0]);
    float m = -1e30f, l = 0.f;
    f32x2 acc = {0.f, 0.f};
    for (int p = p0; p < p1; p += UN) {
      int sA[UN], eA[UN];
#pragma unroll
      for (int j = 0; j < UN; j++) {               // clamped, wave-uniform -> SGPRs
        int pj = (p + j < p1) ? p + j : p1 - 1;
        int2 se = epack[pj];
        sA[j] = __builtin_amdgcn_readfirstlane(se.x);
        eA[j] = __builtin_amdgcn_readfirstlane(se.y);
      }
      f32x2 xs[UN];
#pragma unroll
      for (int j = 0; j < UN; j++)                 // 8 gathers in flight
        xs[j] = ldbf2(&xl[(size_t)sA[j] * HC + c0]);
      float part[UN];
#pragma unroll
      for (int j = 0; j < UN; j++) {
        f32x2 ew = edge_ew(eA[j]);
        f32x2 t = xs[j] + xd + ew;
        float t0 = t.x > 0.f ? t.x : NS * t.x;
        float t1 = t.y > 0.f ? t.y : NS * t.y;
        float pt = t0 * at0 + t1 * at1;
#pragma unroll
        for (int off = 1; off < RED; off <<= 1) pt += __shfl_xor(pt, off);
        part[j] = (p + j < p1) ? pt : -1e30f;      // mask invalid slots
      }
      float mn = m;
#pragma unroll
      for (int j = 0; j < UN; j++) mn = fmaxf(mn, part[j]);
      float sc = __expf(m - mn);
      float asum = 0.f;
      f32x2 ax = {0.f, 0.f};
#pragma unroll
      for (int j = 0; j < UN; j++) {
        float a = __expf(part[j] - mn);            // masked: exp(-inf)=0
        asum += a;
        ax += a * xs[j];
      }
      l = l * sc + asum;
      acc = acc * sc + ax;
      m = mn;
    }
    float inv = 1.f / (l + 1e-16f);
    f32x2 v = {acc.x * inv + b0, acc.y * inv + b1};
    stbf2(&out[(size_t)i * HC + c0], v);
  }
}

// ------- layer 3 GEMV (with fused BN+ELU on h2) -------
__global__ __launch_bounds__(256) void k_gemv3(const u16* __restrict__ h2,
                                               const float2* __restrict__ coef,
                                               const float* __restrict__ W3l, const float* __restrict__ b3l,
                                               const float* __restrict__ W3r, const float* __restrict__ b3r,
                                               float* __restrict__ xl3, float* __restrict__ xr3) {
  int lane = threadIdx.x & 63;
  int i = (blockIdx.x << 2) + (threadIdx.x >> 6);
  if (i >= Nn) return;
  float2 ca = coef[lane], cb = coef[64 + lane];
  float a = b2f(h2[(long)i * HC2 + lane]) * ca.x + ca.y;
  a = a > 0.f ? a : __expf(a) - 1.f;
  float b = b2f(h2[(long)i * HC2 + 64 + lane]) * cb.x + cb.y;
  b = b > 0.f ? b : __expf(b) - 1.f;
  float pl = a * W3l[lane] + b * W3l[64 + lane];
  float pr = a * W3r[lane] + b * W3r[64 + lane];
  for (int o = 1; o < 64; o <<= 1) { pl += __shfl_xor(pl, o); pr += __shfl_xor(pr, o); }
  if (lane == 0) { xl3[i] = pl + b3l[0]; xr3[i] = pr + b3r[0]; }
}

// 16 lanes per node (4 nodes/wave); per-lane online softmax then 16-lane merge
__global__ __launch_bounds__(256) void k_final3(
    const int* __restrict__ rowptr, const int2* __restrict__ epack,
    const float* __restrict__ xl3, const float* __restrict__ xr3,
    const float* __restrict__ We3, const float* __restrict__ att3,
    const float* __restrict__ edge_attr, const float* __restrict__ ea_mean,
    const float* __restrict__ bo3, float* __restrict__ out) {
  int tid = threadIdx.x;
  int sub = tid & 15;
  int i = blockIdx.x * 16 + (tid >> 4);
  if (i >= Nn) return;
  float we[FE];
#pragma unroll
  for (int k4 = 0; k4 < 4; k4++) {
    float4 u = reinterpret_cast<const float4*>(We3)[k4];
    we[4 * k4] = u.x; we[4 * k4 + 1] = u.y; we[4 * k4 + 2] = u.z; we[4 * k4 + 3] = u.w;
  }
  float at = att3[0];
  float ews = 0.f;
#pragma unroll
  for (int k = 0; k < FE; k++) ews += ea_mean[k] * we[k];
  float xd = xr3[i];
  int p0 = rowptr[i], p1 = rowptr[i + 1];
  float m = -1e30f, l = 0.f, o = 0.f;
  for (int p = p0 + sub; p < p1; p += 16) {
    int2 se = epack[p];
    int s = se.x, eid = se.y;
    float ew;
    if (eid < Ee) {
      const float4* ep = reinterpret_cast<const float4*>(&edge_attr[(size_t)eid * FE]);
      ew = 0.f;
#pragma unroll
      for (int k4 = 0; k4 < 4; k4++) {
        float4 u = ep[k4];
        ew += u.x * we[4 * k4] + u.y * we[4 * k4 + 1] + u.z * we[4 * k4 + 2] + u.w * we[4 * k4 + 3];
      }
    } else ew = ews;
    float xsv = xl3[s];
    float t = xsv + xd + ew;
    float v = t > 0.f ? t : NS * t;
    float logit = v * at;
    float mn = fmaxf(m, logit);
    float sc = __expf(m - mn);
    float a = __expf(logit - mn);
    l = l * sc + a;
    o = o * sc + a * xsv;
    m = mn;
  }
  // merge within the 16-lane node group (lane-aligned, stays inside the wave)
  float M = m;
#pragma unroll
  for (int off = 1; off < 16; off <<= 1) M = fmaxf(M, __shfl_xor(M, off));
  float adj = __expf(m - M);
  float lw = l * adj, ow = o * adj;
#pragma unroll
  for (int off = 1; off < 16; off <<= 1) { lw += __shfl_xor(lw, off); ow += __shfl_xor(ow, off); }
  if (sub == 0) out[i] = ow / (lw + 1e-16f) + bo3[0];
}

extern "C" void kernel_launch(void* const* d_in, const int* in_sizes, int n_in,
                              void* d_out, int out_size, void* d_ws, size_t ws_size,
                              hipStream_t stream) {
  const float* x    = (const float*)d_in[0];
  const int*   ei   = (const int*)d_in[1];
  const float* ea   = (const float*)d_in[2];
  const float* W1   = (const float*)d_in[3];
  const float* b1   = (const float*)d_in[4];
  const float* We1  = (const float*)d_in[5];
  const float* att1 = (const float*)d_in[6];
  const float* bo1  = (const float*)d_in[7];
  const float* g1   = (const float*)d_in[8];
  const float* bt1  = (const float*)d_in[9];
  const float* W2   = (const float*)d_in[10];
  const float* b2   = (const float*)d_in[11];
  const float* We2  = (const float*)d_in[12];
  const float* att2 = (const float*)d_in[13];
  const float* bo2  = (const float*)d_in[14];
  const float* g2   = (const float*)d_in[15];
  const float* bt2  = (const float*)d_in[16];
  const float* W3l  = (const float*)d_in[17];
  const float* b3l  = (const float*)d_in[18];
  const float* W3r  = (const float*)d_in[19];
  const float* b3r  = (const float*)d_in[20];
  const float* We3  = (const float*)d_in[21];
  const float* att3 = (const float*)d_in[22];
  const float* bo3  = (const float*)d_in[23];
  float* out = (float*)d_out;

  char* ws = (char*)d_ws;
  size_t off = 0;
  auto alloc = [&](size_t bytes) -> void* {
    void* p = ws + off;
    off = (off + bytes + 255) & ~(size_t)255;
    return p;
  };
  int*    deg     = (int*)alloc((size_t)Nn * 4);
  int*    rowptr  = (int*)alloc((size_t)(Nn + 1) * 4);
  int*    cursor  = (int*)alloc((size_t)Nn * 4);
  int2*   epack   = (int2*)alloc((size_t)ET * 8);
  float*  ea_mean = (float*)alloc((size_t)FE * 4);
  float*  psum    = (float*)alloc((size_t)BNB * 256 * 4);
  float*  psq     = (float*)alloc((size_t)BNB * 256 * 4);
  float2* bncoef  = (float2*)alloc(256 * 8);
  float*  xl3     = (float*)alloc((size_t)Nn * 4);
  float*  xr3     = (float*)alloc((size_t)Nn * 4);
  u16*    xlA     = (u16*)alloc((size_t)Nn * 256 * 2);   // xl1 / xl2 (bf16 internal)
  u16*    hB      = (u16*)alloc((size_t)Nn * 256 * 2);   // h1 / h2 (bf16 internal, pre-BN)
  // total ≈ 57.5 MB

  hipMemsetAsync(deg, 0, (size_t)Nn * 4, stream);
  hipMemsetAsync(cursor, 0, (size_t)Nn * 4, stream);
  hipMemsetAsync(ea_mean, 0, (size_t)FE * 4, stream);

  k_ea_mean<<<400, 256, 0, stream>>>(ea, ea_mean);
  k_deg<<<(ET + 255) / 256, 256, 0, stream>>>(ei, deg);
  k_scan<<<1, 1024, 0, stream>>>(deg, rowptr);
  k_scatter<<<(ET + 255) / 256, 256, 0, stream>>>(ei, rowptr, cursor, epack);

  // ---- layer 1 ----
  k_gemm_mfma<FIN, HC1, float, false><<<dim3(HC1 / 64, (Nn + 63) / 64), 256, 0, stream>>>(
      x, W1, b1, xlA, nullptr, Nn);
  k_node_attn<HC1, C1, 2><<<2048, 256, 0, stream>>>(rowptr, epack, xlA, We1, att1,
                                                    ea, ea_mean, bo1, hB);
  k_bn_stats<HC1><<<BNB, 256, 0, stream>>>(hB, psum, psq);
  k_bn_coef<<<1, 256, 0, stream>>>(psum, psq, g1, bt1, bncoef, HC1);

  // ---- layer 2 (BN1+ELU fused into A-load) ----
  k_gemm_mfma<HC1, HC2, u16, true><<<dim3(HC2 / 64, (Nn + 63) / 64), 256, 0, stream>>>(
      hB, W2, b2, xlA, bncoef, Nn);
  k_node_attn<HC2, C2, 1><<<2048, 256, 0, stream>>>(rowptr, epack, xlA, We2, att2,
                                                    ea, ea_mean, bo2, hB);
  k_bn_stats<HC2><<<BNB, 256, 0, stream>>>(hB, psum, psq);
  k_bn_coef<<<1, 256, 0, stream>>>(psum, psq, g2, bt2, bncoef, HC2);

  // ---- layer 3 (BN2+ELU fused into h2 load) ----
  k_gemv3<<<(Nn + 3) / 4, 256, 0, stream>>>(hB, bncoef, W3l, b3l, W3r, b3r, xl3, xr3);
  k_final3<<<(Nn + 15) / 16, 256, 0, stream>>>(rowptr, epack, xl3, xr3, We3, att3,
                                               ea, ea_mean, bo3, out);
}

// Round 11
// 789.287 us; speedup vs baseline: 1.2514x; 1.2514x over previous
//
#include <hip/hip_runtime.h>

typedef unsigned short u16;   // raw bf16 bits (INTERNAL storage only)
typedef __attribute__((ext_vector_type(4))) float f32x4;
typedef __attribute__((ext_vector_type(2))) float f32x2;
typedef __attribute__((ext_vector_type(8))) short bf16x8;

constexpr int Nn  = 50000;
constexpr int Ee  = 500000;
constexpr int ET  = Nn + Ee;      // edges incl. self-loops
constexpr int FIN = 128;
constexpr int FE  = 16;
constexpr int Hh  = 8;
constexpr int C1  = 32, HC1 = 256;
constexpr int C2  = 16, HC2 = 128;
constexpr float NS  = 0.2f;
constexpr float EPS = 1e-5f;

__device__ __forceinline__ float b2f(u16 u) { return __uint_as_float(((unsigned)u) << 16); }
__device__ __forceinline__ u16 f2b(float f) {
  unsigned u = __float_as_uint(f);
  u += 0x7FFF + ((u >> 16) & 1);          // round-to-nearest-even
  return (u16)(u >> 16);
}
__device__ __forceinline__ f32x2 ldbf2(const u16* p) {
  ushort2 u = *reinterpret_cast<const ushort2*>(p);
  return (f32x2){b2f(u.x), b2f(u.y)};
}
__device__ __forceinline__ void stbf2(u16* p, f32x2 v) {
  ushort2 u; u.x = f2b(v.x); u.y = f2b(v.y);
  *reinterpret_cast<ushort2*>(p) = u;
}

// ---------------- edge_attr mean (for self-loop fill) ----------------
__global__ void k_ea_mean(const float* __restrict__ ea, float* __restrict__ ea_mean) {
  __shared__ float s[256];
  int f  = threadIdx.x & 15;
  int r0 = (threadIdx.x >> 4) + blockIdx.x * 16;
  float acc = 0.f;
  for (int e = r0; e < Ee; e += gridDim.x * 16) acc += ea[e * FE + f];
  s[threadIdx.x] = acc;
  __syncthreads();
  if (threadIdx.x < 16) {
    float t = 0.f;
    for (int r = 0; r < 16; r++) t += s[r * 16 + threadIdx.x];
    atomicAdd(&ea_mean[threadIdx.x], t * (1.f / Ee));
  }
}

// ---------------- CSR build (by destination) ----------------
__global__ void k_deg(const int* __restrict__ ei, int* __restrict__ deg) {
  int e = blockIdx.x * 256 + threadIdx.x;
  if (e >= ET) return;
  int d = (e < Ee) ? ei[Ee + e] : (e - Ee);
  if ((unsigned)d >= (unsigned)Nn) d = 0;   // safety clamp
  atomicAdd(&deg[d], 1);
}

__global__ __launch_bounds__(1024) void k_scan(const int* __restrict__ deg, int* __restrict__ rowptr) {
  const int T = 1024;
  int t = threadIdx.x;
  const int CH = (Nn + T - 1) / T;  // 49
  int base = t * CH;
  int sum = 0;
  for (int i = 0; i < CH; i++) {
    int idx = base + i;
    if (idx < Nn) sum += deg[idx];
  }
  __shared__ int s[T];
  s[t] = sum;
  __syncthreads();
  for (int off = 1; off < T; off <<= 1) {
    int v = (t >= off) ? s[t - off] : 0;
    __syncthreads();
    s[t] += v;
    __syncthreads();
  }
  int run = (t == 0) ? 0 : s[t - 1];
  for (int i = 0; i < CH; i++) {
    int idx = base + i;
    if (idx < Nn) { rowptr[idx] = run; run += deg[idx]; }
  }
  if (t == T - 1) rowptr[Nn] = run;  // == ET
}

__global__ void k_scatter(const int* __restrict__ ei, const int* __restrict__ rowptr,
                          int* __restrict__ cursor, int2* __restrict__ epack) {
  int e = blockIdx.x * 256 + threadIdx.x;
  if (e >= ET) return;
  int s, d;
  if (e < Ee) { s = ei[e]; d = ei[Ee + e]; } else { s = d = e - Ee; }
  if ((unsigned)s >= (unsigned)Nn) s = 0;   // safety clamp
  if ((unsigned)d >= (unsigned)Nn) d = 0;
  int pos = rowptr[d] + atomicAdd(&cursor[d], 1);
  epack[pos] = make_int2(s, e);
}

// ---------------- BN coefficients: scale/shift per channel ----------------
__global__ void k_bn_coef(const float* __restrict__ sum, const float* __restrict__ sq,
                          const float* __restrict__ g, const float* __restrict__ bt,
                          float2* __restrict__ coef, int HC) {
  int ch = threadIdx.x;
  if (ch >= HC) return;
  float mu = sum[ch] * (1.f / Nn);
  float var = sq[ch] * (1.f / Nn) - mu * mu;
  float rs = rsqrtf(var + EPS);
  float sc = g[ch] * rs;
  coef[ch] = make_float2(sc, bt[ch] - sc * mu);
}

// ---------------- batchnorm stats (atomics; cheap) ----------------
template <int HC>
__global__ void k_bn_stats(const u16* __restrict__ x, float* __restrict__ sum, float* __restrict__ sq) {
  long e0 = (long)blockIdx.x * 256 + threadIdx.x;
  long stride = (long)gridDim.x * 256;  // multiple of HC
  float s = 0.f, s2 = 0.f;
  for (long e = e0; e < (long)Nn * HC; e += stride) {
    float v = b2f(x[e]);
    s += v; s2 += v * v;
  }
  int ch = (int)(e0 % HC);
  atomicAdd(&sum[ch], s);
  atomicAdd(&sq[ch], s2);
}

// ------- MFMA bf16 GEMM: C[M,NN] = act(A)[M,KK] @ W[KK,NN] + bias; C stored bf16 -------
template <int KK, int NN, typename AT, bool FUSE>
__global__ __launch_bounds__(256) void k_gemm_mfma(const AT* __restrict__ A, const float* __restrict__ W,
                                                   const float* __restrict__ bias, u16* __restrict__ C,
                                                   const float2* __restrict__ coef, int M) {
  constexpr int WT = KK + 8;
  __shared__ u16 Wt[64 * WT];
  int tid = threadIdx.x;
  int col0 = blockIdx.x * 64;
  int row0 = blockIdx.y * 64;
  for (int idx = tid; idx < KK * 64; idx += 256) {   // stage W -> LDS (transposed, bf16)
    int k = idx >> 6, c = idx & 63;
    Wt[c * WT + k] = f2b(W[(size_t)k * NN + col0 + c]);
  }
  __syncthreads();
  int lane = tid & 63;
  int w = tid >> 6;
  int mr = lane & 15, quad = lane >> 4;
  int row = row0 + w * 16 + mr;
  f32x4 acc[4];
#pragma unroll
  for (int t = 0; t < 4; t++) acc[t] = (f32x4){0.f, 0.f, 0.f, 0.f};
  union Frag { bf16x8 v; u16 u[8]; };
  for (int kb = 0; kb < KK; kb += 32) {
    Frag a;
    if (row < M) {
      if constexpr (sizeof(AT) == 4) {               // fp32 input -> convert
        const float* ap = (const float*)&A[(size_t)row * KK + kb + quad * 8];
        float4 a0 = *reinterpret_cast<const float4*>(ap);
        float4 a1 = *reinterpret_cast<const float4*>(ap + 4);
        a.u[0] = f2b(a0.x); a.u[1] = f2b(a0.y); a.u[2] = f2b(a0.z); a.u[3] = f2b(a0.w);
        a.u[4] = f2b(a1.x); a.u[5] = f2b(a1.y); a.u[6] = f2b(a1.z); a.u[7] = f2b(a1.w);
      } else {                                       // bf16 internal
        a.v = *reinterpret_cast<const bf16x8*>(&A[(size_t)row * KK + kb + quad * 8]);
        if constexpr (FUSE) {
          int k0 = kb + quad * 8;
#pragma unroll
          for (int j = 0; j < 8; j++) {
            float2 c2 = coef[k0 + j];
            float y = b2f(a.u[j]) * c2.x + c2.y;
            y = y > 0.f ? y : __expf(y) - 1.f;       // ELU
            a.u[j] = f2b(y);
          }
        }
      }
    } else {
#pragma unroll
      for (int j = 0; j < 8; j++) a.u[j] = 0;
    }
#pragma unroll
    for (int t = 0; t < 4; t++) {
      const bf16x8* bp = reinterpret_cast<const bf16x8*>(&Wt[(t * 16 + mr) * WT + kb + quad * 8]);
      acc[t] = __builtin_amdgcn_mfma_f32_16x16x32_bf16(a.v, *bp, acc[t], 0, 0, 0);
    }
  }
  int orow = row0 + w * 16 + quad * 4;
#pragma unroll
  for (int t = 0; t < 4; t++) {
    int col = col0 + t * 16 + mr;
    float bs = bias[col];
#pragma unroll
    for (int r = 0; r < 4; r++) {
      int rr = orow + r;
      if (rr < M) C[(size_t)rr * NN + col] = f2b(acc[t][r] + bs);
    }
  }
}

// ---- fused GATv2 attention: logits + online softmax + aggregation ----
// UN=4 MASKED batches (pad to x4, clamp index, part=-1e30) -> no serial tail, ~13% pad waste.
template <int HC, int C, int WPN>
__global__ __launch_bounds__(256) void k_node_attn(
    const int* __restrict__ rowptr, const int2* __restrict__ epack,
    const u16* __restrict__ xl, const float* __restrict__ We, const float* __restrict__ att,
    const float* __restrict__ edge_attr, const float* __restrict__ ea_mean,
    const float* __restrict__ bo, u16* __restrict__ out) {
  int lane = threadIdx.x & 63;
  int gwid = (blockIdx.x << 2) + (threadIdx.x >> 6);
  int nwaves = gridDim.x << 2;          // multiple of WPN by launch config
  int w = gwid % WPN;
  int i0 = gwid / WPN;
  int istride = nwaves / WPN;
  int c0 = w * 128 + lane * 2;
  f32x2 w2[FE];
#pragma unroll
  for (int k = 0; k < FE; k++) {
    float2 t = *reinterpret_cast<const float2*>(&We[k * HC + c0]);
    w2[k] = (f32x2){t.x, t.y};
  }
  float at0 = att[c0], at1 = att[c0 + 1];
  f32x2 ews2 = {0.f, 0.f};
#pragma unroll
  for (int k = 0; k < FE; k++) ews2 += ea_mean[k] * w2[k];
  float b0 = bo[c0], b1 = bo[c0 + 1];
  constexpr int RED = C / 2;                       // lanes per head
  constexpr int UN = 4;

  auto edge_ew = [&](int eid) -> f32x2 {
    if (eid < Ee) {                                // scalar (uniform) branch
      const float4* ep = reinterpret_cast<const float4*>(&edge_attr[(size_t)eid * FE]);
      f32x2 a = {0.f, 0.f};
#pragma unroll
      for (int k4 = 0; k4 < 4; k4++) {
        float4 u = ep[k4];
        a += u.x * w2[4 * k4 + 0];
        a += u.y * w2[4 * k4 + 1];
        a += u.z * w2[4 * k4 + 2];
        a += u.w * w2[4 * k4 + 3];
      }
      return a;
    }
    return ews2;
  };

  for (int i = i0; i < Nn; i += istride) {
    int p0 = rowptr[i], p1 = rowptr[i + 1];      // deg >= 1 (self-loop)
    f32x2 xd = ldbf2(&xl[(size_t)i * HC + c0]);
    float m = -1e30f, l = 0.f;
    f32x2 acc = {0.f, 0.f};
    for (int p = p0; p < p1; p += UN) {
      int sA[UN], eA[UN];
#pragma unroll
      for (int j = 0; j < UN; j++) {               // clamped, wave-uniform -> SGPRs
        int pj = (p + j < p1) ? p + j : p1 - 1;
        int2 se = epack[pj];
        sA[j] = __builtin_amdgcn_readfirstlane(se.x);
        eA[j] = __builtin_amdgcn_readfirstlane(se.y);
      }
      f32x2 xs[UN];
#pragma unroll
      for (int j = 0; j < UN; j++)                 // 4 gathers in flight
        xs[j] = ldbf2(&xl[(size_t)sA[j] * HC + c0]);
      float part[UN];
#pragma unroll
      for (int j = 0; j < UN; j++) {
        f32x2 ew = edge_ew(eA[j]);
        f32x2 t = xs[j] + xd + ew;
        float t0 = t.x > 0.f ? t.x : NS * t.x;
        float t1 = t.y > 0.f ? t.y : NS * t.y;
        float pt = t0 * at0 + t1 * at1;
#pragma unroll
        for (int off = 1; off < RED; off <<= 1) pt += __shfl_xor(pt, off);
        part[j] = (p + j < p1) ? pt : -1e30f;      // mask padded slots
      }
      float mn = m;
#pragma unroll
      for (int j = 0; j < UN; j++) mn = fmaxf(mn, part[j]);
      float sc = __expf(m - mn);
      float asum = 0.f;
      f32x2 ax = {0.f, 0.f};
#pragma unroll
      for (int j = 0; j < UN; j++) {
        float a = __expf(part[j] - mn);            // masked: exp(-inf)=0
        asum += a;
        ax += a * xs[j];
      }
      l = l * sc + asum;
      acc = acc * sc + ax;
      m = mn;
    }
    float inv = 1.f / (l + 1e-16f);
    f32x2 v = {acc.x * inv + b0, acc.y * inv + b1};
    stbf2(&out[(size_t)i * HC + c0], v);
  }
}

// ------- layer 3 GEMV (with fused BN+ELU on h2) -------
__global__ __launch_bounds__(256) void k_gemv3(const u16* __restrict__ h2,
                                               const float2* __restrict__ coef,
                                               const float* __restrict__ W3l, const float* __restrict__ b3l,
                                               const float* __restrict__ W3r, const float* __restrict__ b3r,
                                               float* __restrict__ xl3, float* __restrict__ xr3) {
  int lane = threadIdx.x & 63;
  int i = (blockIdx.x << 2) + (threadIdx.x >> 6);
  if (i >= Nn) return;
  float2 ca = coef[lane], cb = coef[64 + lane];
  float a = b2f(h2[(long)i * HC2 + lane]) * ca.x + ca.y;
  a = a > 0.f ? a : __expf(a) - 1.f;
  float b = b2f(h2[(long)i * HC2 + 64 + lane]) * cb.x + cb.y;
  b = b > 0.f ? b : __expf(b) - 1.f;
  float pl = a * W3l[lane] + b * W3l[64 + lane];
  float pr = a * W3r[lane] + b * W3r[64 + lane];
  for (int o = 1; o < 64; o <<= 1) { pl += __shfl_xor(pl, o); pr += __shfl_xor(pr, o); }
  if (lane == 0) { xl3[i] = pl + b3l[0]; xr3[i] = pr + b3r[0]; }
}

// wave per node; lanes split edges; per-lane online softmax then cross-lane merge
__global__ __launch_bounds__(256) void k_final3(
    const int* __restrict__ rowptr, const int2* __restrict__ epack,
    const float* __restrict__ xl3, const float* __restrict__ xr3,
    const float* __restrict__ We3, const float* __restrict__ att3,
    const float* __restrict__ edge_attr, const float* __restrict__ ea_mean,
    const float* __restrict__ bo3, float* __restrict__ out) {
  int lane = threadIdx.x & 63;
  int i = (blockIdx.x << 2) + (threadIdx.x >> 6);
  if (i >= Nn) return;
  float we[FE];
#pragma unroll
  for (int k4 = 0; k4 < 4; k4++) {
    float4 u = reinterpret_cast<const float4*>(We3)[k4];
    we[4 * k4] = u.x; we[4 * k4 + 1] = u.y; we[4 * k4 + 2] = u.z; we[4 * k4 + 3] = u.w;
  }
  float at = att3[0];
  float ews = 0.f;
#pragma unroll
  for (int k = 0; k < FE; k++) ews += ea_mean[k] * we[k];
  float xd = xr3[i];
  int p0 = rowptr[i], p1 = rowptr[i + 1];
  float m = -1e30f, l = 0.f, o = 0.f;
  for (int p = p0 + lane; p < p1; p += 64) {
    int2 se = epack[p];
    int s = se.x, eid = se.y;
    float ew;
    if (eid < Ee) {
      const float4* ep = reinterpret_cast<const float4*>(&edge_attr[(size_t)eid * FE]);
      ew = 0.f;
#pragma unroll
      for (int k4 = 0; k4 < 4; k4++) {
        float4 u = ep[k4];
        ew += u.x * we[4 * k4] + u.y * we[4 * k4 + 1] + u.z * we[4 * k4 + 2] + u.w * we[4 * k4 + 3];
      }
    } else ew = ews;
    float xsv = xl3[s];
    float t = xsv + xd + ew;
    float v = t > 0.f ? t : NS * t;
    float logit = v * at;
    float mn = fmaxf(m, logit);
    float sc = __expf(m - mn);
    float a = __expf(logit - mn);
    l = l * sc + a;
    o = o * sc + a * xsv;
    m = mn;
  }
  // cross-lane merge
  float M = m;
#pragma unroll
  for (int off = 1; off < 64; off <<= 1) M = fmaxf(M, __shfl_xor(M, off));
  float adj = __expf(m - M);                       // lanes with no edges: 0
  float lw = l * adj, ow = o * adj;
#pragma unroll
  for (int off = 1; off < 64; off <<= 1) { lw += __shfl_xor(lw, off); ow += __shfl_xor(ow, off); }
  if (lane == 0) out[i] = ow / (lw + 1e-16f) + bo3[0];
}

extern "C" void kernel_launch(void* const* d_in, const int* in_sizes, int n_in,
                              void* d_out, int out_size, void* d_ws, size_t ws_size,
                              hipStream_t stream) {
  const float* x    = (const float*)d_in[0];
  const int*   ei   = (const int*)d_in[1];
  const float* ea   = (const float*)d_in[2];
  const float* W1   = (const float*)d_in[3];
  const float* b1   = (const float*)d_in[4];
  const float* We1  = (const float*)d_in[5];
  const float* att1 = (const float*)d_in[6];
  const float* bo1  = (const float*)d_in[7];
  const float* g1   = (const float*)d_in[8];
  const float* bt1  = (const float*)d_in[9];
  const float* W2   = (const float*)d_in[10];
  const float* b2   = (const float*)d_in[11];
  const float* We2  = (const float*)d_in[12];
  const float* att2 = (const float*)d_in[13];
  const float* bo2  = (const float*)d_in[14];
  const float* g2   = (const float*)d_in[15];
  const float* bt2  = (const float*)d_in[16];
  const float* W3l  = (const float*)d_in[17];
  const float* b3l  = (const float*)d_in[18];
  const float* W3r  = (const float*)d_in[19];
  const float* b3r  = (const float*)d_in[20];
  const float* We3  = (const float*)d_in[21];
  const float* att3 = (const float*)d_in[22];
  const float* bo3  = (const float*)d_in[23];
  float* out = (float*)d_out;

  char* ws = (char*)d_ws;
  size_t off = 0;
  auto alloc = [&](size_t bytes) -> void* {
    void* p = ws + off;
    off = (off + bytes + 255) & ~(size_t)255;
    return p;
  };
  int*    deg     = (int*)alloc((size_t)Nn * 4);
  int*    rowptr  = (int*)alloc((size_t)(Nn + 1) * 4);
  int*    cursor  = (int*)alloc((size_t)Nn * 4);
  int2*   epack   = (int2*)alloc((size_t)ET * 8);
  float*  ea_mean = (float*)alloc((size_t)FE * 4);
  float*  bn_sum  = (float*)alloc(256 * 4);
  float*  bn_sq   = (float*)alloc(256 * 4);
  float2* bncoef  = (float2*)alloc(256 * 8);
  float*  xl3     = (float*)alloc((size_t)Nn * 4);
  float*  xr3     = (float*)alloc((size_t)Nn * 4);
  u16*    xlA     = (u16*)alloc((size_t)Nn * 256 * 2);   // xl1 / xl2 (bf16 internal)
  u16*    hB      = (u16*)alloc((size_t)Nn * 256 * 2);   // h1 / h2 (bf16 internal, pre-BN)
  // total ≈ 57 MB

  hipMemsetAsync(deg, 0, (size_t)Nn * 4, stream);
  hipMemsetAsync(cursor, 0, (size_t)Nn * 4, stream);
  hipMemsetAsync(ea_mean, 0, (size_t)FE * 4, stream);

  k_ea_mean<<<400, 256, 0, stream>>>(ea, ea_mean);
  k_deg<<<(ET + 255) / 256, 256, 0, stream>>>(ei, deg);
  k_scan<<<1, 1024, 0, stream>>>(deg, rowptr);
  k_scatter<<<(ET + 255) / 256, 256, 0, stream>>>(ei, rowptr, cursor, epack);

  // ---- layer 1 ----
  k_gemm_mfma<FIN, HC1, float, false><<<dim3(HC1 / 64, (Nn + 63) / 64), 256, 0, stream>>>(
      x, W1, b1, xlA, nullptr, Nn);
  k_node_attn<HC1, C1, 2><<<2048, 256, 0, stream>>>(rowptr, epack, xlA, We1, att1,
                                                    ea, ea_mean, bo1, hB);
  hipMemsetAsync(bn_sum, 0, 256 * 4, stream);
  hipMemsetAsync(bn_sq, 0, 256 * 4, stream);
  k_bn_stats<HC1><<<256, 256, 0, stream>>>(hB, bn_sum, bn_sq);
  k_bn_coef<<<1, 256, 0, stream>>>(bn_sum, bn_sq, g1, bt1, bncoef, HC1);

  // ---- layer 2 (BN1+ELU fused into A-load) ----
  k_gemm_mfma<HC1, HC2, u16, true><<<dim3(HC2 / 64, (Nn + 63) / 64), 256, 0, stream>>>(
      hB, W2, b2, xlA, bncoef, Nn);
  k_node_attn<HC2, C2, 1><<<2048, 256, 0, stream>>>(rowptr, epack, xlA, We2, att2,
                                                    ea, ea_mean, bo2, hB);
  hipMemsetAsync(bn_sum, 0, 256 * 4, stream);
  hipMemsetAsync(bn_sq, 0, 256 * 4, stream);
  k_bn_stats<HC2><<<256, 256, 0, stream>>>(hB, bn_sum, bn_sq);
  k_bn_coef<<<1, 256, 0, stream>>>(bn_sum, bn_sq, g2, bt2, bncoef, HC2);

  // ---- layer 3 (BN2+ELU fused into h2 load) ----
  k_gemv3<<<(Nn + 3) / 4, 256, 0, stream>>>(hB, bncoef, W3l, b3l, W3r, b3r, xl3, xr3);
  k_final3<<<(Nn + 3) / 4, 256, 0, stream>>>(rowptr, epack, xl3, xr3, We3, att3,
                                             ea, ea_mean, bo3, out);
}

// Round 12
// 759.882 us; speedup vs baseline: 1.2999x; 1.0387x over previous
//
#include <hip/hip_runtime.h>

typedef unsigned short u16;   // raw bf16 bits (INTERNAL storage only)
typedef __attribute__((ext_vector_type(4))) float f32x4;
typedef __attribute__((ext_vector_type(2))) float f32x2;
typedef __attribute__((ext_vector_type(8))) short bf16x8;

constexpr int Nn  = 50000;
constexpr int Ee  = 500000;
constexpr int ET  = Nn + Ee;      // edges incl. self-loops
constexpr int FIN = 128;
constexpr int FE  = 16;
constexpr int Hh  = 8;
constexpr int C1  = 32, HC1 = 256;
constexpr int C2  = 16, HC2 = 128;
constexpr float NS  = 0.2f;
constexpr float EPS = 1e-5f;

__device__ __forceinline__ float b2f(u16 u) { return __uint_as_float(((unsigned)u) << 16); }
__device__ __forceinline__ u16 f2b(float f) {
  unsigned u = __float_as_uint(f);
  u += 0x7FFF + ((u >> 16) & 1);          // round-to-nearest-even
  return (u16)(u >> 16);
}
__device__ __forceinline__ f32x2 ldbf2(const u16* p) {
  ushort2 u = *reinterpret_cast<const ushort2*>(p);
  return (f32x2){b2f(u.x), b2f(u.y)};
}
__device__ __forceinline__ void stbf2(u16* p, f32x2 v) {
  ushort2 u; u.x = f2b(v.x); u.y = f2b(v.y);
  *reinterpret_cast<ushort2*>(p) = u;
}

// ---------------- init: zero all accumulators in ONE dispatch (replaces 7 memsets) ----
__global__ void k_init(int* __restrict__ deg, int* __restrict__ cursor, float* __restrict__ ea_mean,
                       float* __restrict__ bn1s, float* __restrict__ bn1q,
                       float* __restrict__ bn2s, float* __restrict__ bn2q) {
  int t = blockIdx.x * 256 + threadIdx.x;
  int stride = gridDim.x * 256;
  for (int i = t; i < Nn; i += stride) { deg[i] = 0; cursor[i] = 0; }
  if (t < FE) ea_mean[t] = 0.f;
  if (t >= 64 && t < 64 + HC1) { bn1s[t - 64] = 0.f; bn1q[t - 64] = 0.f; }
  if (t >= 384 && t < 384 + HC2) { bn2s[t - 384] = 0.f; bn2q[t - 384] = 0.f; }
}

// ---------------- merged: degree histogram + edge_attr mean (independent atomics) ----
__global__ void k_deg_mean(const int* __restrict__ ei, const float* __restrict__ ea,
                           int* __restrict__ deg, float* __restrict__ ea_mean) {
  int t = threadIdx.x;
  int e = blockIdx.x * 256 + t;
  if (e < ET) {
    int d = (e < Ee) ? ei[Ee + e] : (e - Ee);
    if ((unsigned)d >= (unsigned)Nn) d = 0;   // safety clamp
    atomicAdd(&deg[d], 1);
  }
  // edge_attr column sums: 16 rows x 16 feats per block
  __shared__ float s[256];
  int f  = t & 15;
  int r0 = (t >> 4) + blockIdx.x * 16;
  float acc = 0.f;
  for (int r = r0; r < Ee; r += gridDim.x * 16) acc += ea[r * FE + f];
  s[t] = acc;
  __syncthreads();
  if (t < 16) {
    float v = 0.f;
    for (int r = 0; r < 16; r++) v += s[r * 16 + t];
    atomicAdd(&ea_mean[t], v * (1.f / Ee));
  }
}

__global__ __launch_bounds__(1024) void k_scan(const int* __restrict__ deg, int* __restrict__ rowptr) {
  const int T = 1024;
  int t = threadIdx.x;
  const int CH = (Nn + T - 1) / T;  // 49
  int base = t * CH;
  int sum = 0;
  for (int i = 0; i < CH; i++) {
    int idx = base + i;
    if (idx < Nn) sum += deg[idx];
  }
  __shared__ int s[T];
  s[t] = sum;
  __syncthreads();
  for (int off = 1; off < T; off <<= 1) {
    int v = (t >= off) ? s[t - off] : 0;
    __syncthreads();
    s[t] += v;
    __syncthreads();
  }
  int run = (t == 0) ? 0 : s[t - 1];
  for (int i = 0; i < CH; i++) {
    int idx = base + i;
    if (idx < Nn) { rowptr[idx] = run; run += deg[idx]; }
  }
  if (t == T - 1) rowptr[Nn] = run;  // == ET
}

__global__ void k_scatter(const int* __restrict__ ei, const int* __restrict__ rowptr,
                          int* __restrict__ cursor, int2* __restrict__ epack) {
  int e = blockIdx.x * 256 + threadIdx.x;
  if (e >= ET) return;
  int s, d;
  if (e < Ee) { s = ei[e]; d = ei[Ee + e]; } else { s = d = e - Ee; }
  if ((unsigned)s >= (unsigned)Nn) s = 0;   // safety clamp
  if ((unsigned)d >= (unsigned)Nn) d = 0;
  int pos = rowptr[d] + atomicAdd(&cursor[d], 1);
  epack[pos] = make_int2(s, e);
}

// ---------------- BN coefficients: scale/shift per channel ----------------
__global__ void k_bn_coef(const float* __restrict__ sum, const float* __restrict__ sq,
                          const float* __restrict__ g, const float* __restrict__ bt,
                          float2* __restrict__ coef, int HC) {
  int ch = threadIdx.x;
  if (ch >= HC) return;
  float mu = sum[ch] * (1.f / Nn);
  float var = sq[ch] * (1.f / Nn) - mu * mu;
  float rs = rsqrtf(var + EPS);
  float sc = g[ch] * rs;
  coef[ch] = make_float2(sc, bt[ch] - sc * mu);
}

// ---------------- batchnorm stats (atomics; cheap) ----------------
template <int HC>
__global__ void k_bn_stats(const u16* __restrict__ x, float* __restrict__ sum, float* __restrict__ sq) {
  long e0 = (long)blockIdx.x * 256 + threadIdx.x;
  long stride = (long)gridDim.x * 256;  // multiple of HC
  float s = 0.f, s2 = 0.f;
  for (long e = e0; e < (long)Nn * HC; e += stride) {
    float v = b2f(x[e]);
    s += v; s2 += v * v;
  }
  int ch = (int)(e0 % HC);
  atomicAdd(&sum[ch], s);
  atomicAdd(&sq[ch], s2);
}

// ------- MFMA bf16 GEMM: C[M,NN] = act(A)[M,KK] @ W[KK,NN] + bias; C stored bf16 -------
template <int KK, int NN, typename AT, bool FUSE>
__global__ __launch_bounds__(256) void k_gemm_mfma(const AT* __restrict__ A, const float* __restrict__ W,
                                                   const float* __restrict__ bias, u16* __restrict__ C,
                                                   const float2* __restrict__ coef, int M) {
  constexpr int WT = KK + 8;
  __shared__ u16 Wt[64 * WT];
  int tid = threadIdx.x;
  int col0 = blockIdx.x * 64;
  int row0 = blockIdx.y * 64;
  for (int idx = tid; idx < KK * 64; idx += 256) {   // stage W -> LDS (transposed, bf16)
    int k = idx >> 6, c = idx & 63;
    Wt[c * WT + k] = f2b(W[(size_t)k * NN + col0 + c]);
  }
  __syncthreads();
  int lane = tid & 63;
  int w = tid >> 6;
  int mr = lane & 15, quad = lane >> 4;
  int row = row0 + w * 16 + mr;
  f32x4 acc[4];
#pragma unroll
  for (int t = 0; t < 4; t++) acc[t] = (f32x4){0.f, 0.f, 0.f, 0.f};
  union Frag { bf16x8 v; u16 u[8]; };
  for (int kb = 0; kb < KK; kb += 32) {
    Frag a;
    if (row < M) {
      if constexpr (sizeof(AT) == 4) {               // fp32 input -> convert
        const float* ap = (const float*)&A[(size_t)row * KK + kb + quad * 8];
        float4 a0 = *reinterpret_cast<const float4*>(ap);
        float4 a1 = *reinterpret_cast<const float4*>(ap + 4);
        a.u[0] = f2b(a0.x); a.u[1] = f2b(a0.y); a.u[2] = f2b(a0.z); a.u[3] = f2b(a0.w);
        a.u[4] = f2b(a1.x); a.u[5] = f2b(a1.y); a.u[6] = f2b(a1.z); a.u[7] = f2b(a1.w);
      } else {                                       // bf16 internal
        a.v = *reinterpret_cast<const bf16x8*>(&A[(size_t)row * KK + kb + quad * 8]);
        if constexpr (FUSE) {
          int k0 = kb + quad * 8;
#pragma unroll
          for (int j = 0; j < 8; j++) {
            float2 c2 = coef[k0 + j];
            float y = b2f(a.u[j]) * c2.x + c2.y;
            y = y > 0.f ? y : __expf(y) - 1.f;       // ELU
            a.u[j] = f2b(y);
          }
        }
      }
    } else {
#pragma unroll
      for (int j = 0; j < 8; j++) a.u[j] = 0;
    }
#pragma unroll
    for (int t = 0; t < 4; t++) {
      const bf16x8* bp = reinterpret_cast<const bf16x8*>(&Wt[(t * 16 + mr) * WT + kb + quad * 8]);
      acc[t] = __builtin_amdgcn_mfma_f32_16x16x32_bf16(a.v, *bp, acc[t], 0, 0, 0);
    }
  }
  int orow = row0 + w * 16 + quad * 4;
#pragma unroll
  for (int t = 0; t < 4; t++) {
    int col = col0 + t * 16 + mr;
    float bs = bias[col];
#pragma unroll
    for (int r = 0; r < 4; r++) {
      int rr = orow + r;
      if (rr < M) C[(size_t)rr * NN + col] = f2b(acc[t][r] + bs);
    }
  }
}

// ---- fused GATv2 attention (R9-exact loop): UN=4 batches + serial remainder ----
template <int HC, int C, int WPN>
__global__ __launch_bounds__(256) void k_node_attn(
    const int* __restrict__ rowptr, const int2* __restrict__ epack,
    const u16* __restrict__ xl, const float* __restrict__ We, const float* __restrict__ att,
    const float* __restrict__ edge_attr, const float* __restrict__ ea_mean,
    const float* __restrict__ bo, u16* __restrict__ out) {
  int lane = threadIdx.x & 63;
  int gwid = (blockIdx.x << 2) + (threadIdx.x >> 6);
  int nwaves = gridDim.x << 2;          // multiple of WPN by launch config
  int w = gwid % WPN;
  int i0 = gwid / WPN;
  int istride = nwaves / WPN;
  int c0 = w * 128 + lane * 2;
  f32x2 w2[FE];
#pragma unroll
  for (int k = 0; k < FE; k++) {
    float2 t = *reinterpret_cast<const float2*>(&We[k * HC + c0]);
    w2[k] = (f32x2){t.x, t.y};
  }
  float at0 = att[c0], at1 = att[c0 + 1];
  f32x2 ews2 = {0.f, 0.f};
#pragma unroll
  for (int k = 0; k < FE; k++) ews2 += ea_mean[k] * w2[k];
  float b0 = bo[c0], b1 = bo[c0 + 1];
  constexpr int RED = C / 2;                       // lanes per head
  constexpr int UN = 4;

  auto edge_ew = [&](int eid) -> f32x2 {
    if (eid < Ee) {                                // scalar (uniform) branch
      const float4* ep = reinterpret_cast<const float4*>(&edge_attr[(size_t)eid * FE]);
      f32x2 a = {0.f, 0.f};
#pragma unroll
      for (int k4 = 0; k4 < 4; k4++) {
        float4 u = ep[k4];
        a += u.x * w2[4 * k4 + 0];
        a += u.y * w2[4 * k4 + 1];
        a += u.z * w2[4 * k4 + 2];
        a += u.w * w2[4 * k4 + 3];
      }
      return a;
    }
    return ews2;
  };

  for (int i = i0; i < Nn; i += istride) {
    int p0 = rowptr[i], p1 = rowptr[i + 1];
    f32x2 xd = ldbf2(&xl[(size_t)i * HC + c0]);
    float m = -1e30f, l = 0.f;
    f32x2 acc = {0.f, 0.f};
    int p = p0;
    for (; p + UN <= p1; p += UN) {
      int sA[UN], eA[UN];
#pragma unroll
      for (int j = 0; j < UN; j++) {               // wave-uniform -> SGPRs
        int2 se = epack[p + j];
        sA[j] = __builtin_amdgcn_readfirstlane(se.x);
        eA[j] = __builtin_amdgcn_readfirstlane(se.y);
      }
      f32x2 xs[UN];
#pragma unroll
      for (int j = 0; j < UN; j++)                 // saddr-form coalesced loads
        xs[j] = ldbf2(&xl[(size_t)sA[j] * HC + c0]);
      f32x2 ew[UN];
#pragma unroll
      for (int j = 0; j < UN; j++) ew[j] = edge_ew(eA[j]);
      float part[UN];
#pragma unroll
      for (int j = 0; j < UN; j++) {
        f32x2 t = xs[j] + xd + ew[j];
        float t0 = t.x > 0.f ? t.x : NS * t.x;
        float t1 = t.y > 0.f ? t.y : NS * t.y;
        float pt = t0 * at0 + t1 * at1;
#pragma unroll
        for (int off = 1; off < RED; off <<= 1) pt += __shfl_xor(pt, off);
        part[j] = pt;
      }
      float mn = m;
#pragma unroll
      for (int j = 0; j < UN; j++) mn = fmaxf(mn, part[j]);
      float sc = __expf(m - mn);
      float a[UN], asum = 0.f;
      f32x2 ax = {0.f, 0.f};
#pragma unroll
      for (int j = 0; j < UN; j++) {
        a[j] = __expf(part[j] - mn);
        asum += a[j];
        ax += a[j] * xs[j];
      }
      l = l * sc + asum;
      acc = acc * sc + ax;
      m = mn;
    }
    for (; p < p1; p++) {                          // remainder
      int2 se = epack[p];
      int s = __builtin_amdgcn_readfirstlane(se.x);
      int eid = __builtin_amdgcn_readfirstlane(se.y);
      f32x2 ew = edge_ew(eid);
      f32x2 xs = ldbf2(&xl[(size_t)s * HC + c0]);
      f32x2 t = xs + xd + ew;
      float t0 = t.x > 0.f ? t.x : NS * t.x;
      float t1 = t.y > 0.f ? t.y : NS * t.y;
      float pt = t0 * at0 + t1 * at1;
#pragma unroll
      for (int off = 1; off < RED; off <<= 1) pt += __shfl_xor(pt, off);
      float mn = fmaxf(m, pt);
      float sc = __expf(m - mn);
      float a = __expf(pt - mn);
      l = l * sc + a;
      acc = acc * sc + a * xs;
      m = mn;
    }
    float inv = 1.f / (l + 1e-16f);
    f32x2 v = {acc.x * inv + b0, acc.y * inv + b1};
    stbf2(&out[(size_t)i * HC + c0], v);
  }
}

// ------- layer 3 GEMV (with fused BN+ELU on h2) -------
__global__ __launch_bounds__(256) void k_gemv3(const u16* __restrict__ h2,
                                               const float2* __restrict__ coef,
                                               const float* __restrict__ W3l, const float* __restrict__ b3l,
                                               const float* __restrict__ W3r, const float* __restrict__ b3r,
                                               float* __restrict__ xl3, float* __restrict__ xr3) {
  int lane = threadIdx.x & 63;
  int i = (blockIdx.x << 2) + (threadIdx.x >> 6);
  if (i >= Nn) return;
  float2 ca = coef[lane], cb = coef[64 + lane];
  float a = b2f(h2[(long)i * HC2 + lane]) * ca.x + ca.y;
  a = a > 0.f ? a : __expf(a) - 1.f;
  float b = b2f(h2[(long)i * HC2 + 64 + lane]) * cb.x + cb.y;
  b = b > 0.f ? b : __expf(b) - 1.f;
  float pl = a * W3l[lane] + b * W3l[64 + lane];
  float pr = a * W3r[lane] + b * W3r[64 + lane];
  for (int o = 1; o < 64; o <<= 1) { pl += __shfl_xor(pl, o); pr += __shfl_xor(pr, o); }
  if (lane == 0) { xl3[i] = pl + b3l[0]; xr3[i] = pr + b3r[0]; }
}

// wave per node; lanes split edges; per-lane online softmax then cross-lane merge
__global__ __launch_bounds__(256) void k_final3(
    const int* __restrict__ rowptr, const int2* __restrict__ epack,
    const float* __restrict__ xl3, const float* __restrict__ xr3,
    const float* __restrict__ We3, const float* __restrict__ att3,
    const float* __restrict__ edge_attr, const float* __restrict__ ea_mean,
    const float* __restrict__ bo3, float* __restrict__ out) {
  int lane = threadIdx.x & 63;
  int i = (blockIdx.x << 2) + (threadIdx.x >> 6);
  if (i >= Nn) return;
  float we[FE];
#pragma unroll
  for (int k4 = 0; k4 < 4; k4++) {
    float4 u = reinterpret_cast<const float4*>(We3)[k4];
    we[4 * k4] = u.x; we[4 * k4 + 1] = u.y; we[4 * k4 + 2] = u.z; we[4 * k4 + 3] = u.w;
  }
  float at = att3[0];
  float ews = 0.f;
#pragma unroll
  for (int k = 0; k < FE; k++) ews += ea_mean[k] * we[k];
  float xd = xr3[i];
  int p0 = rowptr[i], p1 = rowptr[i + 1];
  float m = -1e30f, l = 0.f, o = 0.f;
  for (int p = p0 + lane; p < p1; p += 64) {
    int2 se = epack[p];
    int s = se.x, eid = se.y;
    float ew;
    if (eid < Ee) {
      const float4* ep = reinterpret_cast<const float4*>(&edge_attr[(size_t)eid * FE]);
      ew = 0.f;
#pragma unroll
      for (int k4 = 0; k4 < 4; k4++) {
        float4 u = ep[k4];
        ew += u.x * we[4 * k4] + u.y * we[4 * k4 + 1] + u.z * we[4 * k4 + 2] + u.w * we[4 * k4 + 3];
      }
    } else ew = ews;
    float xsv = xl3[s];
    float t = xsv + xd + ew;
    float v = t > 0.f ? t : NS * t;
    float logit = v * at;
    float mn = fmaxf(m, logit);
    float sc = __expf(m - mn);
    float a = __expf(logit - mn);
    l = l * sc + a;
    o = o * sc + a * xsv;
    m = mn;
  }
  float M = m;
#pragma unroll
  for (int off = 1; off < 64; off <<= 1) M = fmaxf(M, __shfl_xor(M, off));
  float adj = __expf(m - M);                       // lanes with no edges: 0
  float lw = l * adj, ow = o * adj;
#pragma unroll
  for (int off = 1; off < 64; off <<= 1) { lw += __shfl_xor(lw, off); ow += __shfl_xor(ow, off); }
  if (lane == 0) out[i] = ow / (lw + 1e-16f) + bo3[0];
}

extern "C" void kernel_launch(void* const* d_in, const int* in_sizes, int n_in,
                              void* d_out, int out_size, void* d_ws, size_t ws_size,
                              hipStream_t stream) {
  const float* x    = (const float*)d_in[0];
  const int*   ei   = (const int*)d_in[1];
  const float* ea   = (const float*)d_in[2];
  const float* W1   = (const float*)d_in[3];
  const float* b1   = (const float*)d_in[4];
  const float* We1  = (const float*)d_in[5];
  const float* att1 = (const float*)d_in[6];
  const float* bo1  = (const float*)d_in[7];
  const float* g1   = (const float*)d_in[8];
  const float* bt1  = (const float*)d_in[9];
  const float* W2   = (const float*)d_in[10];
  const float* b2   = (const float*)d_in[11];
  const float* We2  = (const float*)d_in[12];
  const float* att2 = (const float*)d_in[13];
  const float* bo2  = (const float*)d_in[14];
  const float* g2   = (const float*)d_in[15];
  const float* bt2  = (const float*)d_in[16];
  const float* W3l  = (const float*)d_in[17];
  const float* b3l  = (const float*)d_in[18];
  const float* W3r  = (const float*)d_in[19];
  const float* b3r  = (const float*)d_in[20];
  const float* We3  = (const float*)d_in[21];
  const float* att3 = (const float*)d_in[22];
  const float* bo3  = (const float*)d_in[23];
  float* out = (float*)d_out;

  char* ws = (char*)d_ws;
  size_t off = 0;
  auto alloc = [&](size_t bytes) -> void* {
    void* p = ws + off;
    off = (off + bytes + 255) & ~(size_t)255;
    return p;
  };
  int*    deg     = (int*)alloc((size_t)Nn * 4);
  int*    rowptr  = (int*)alloc((size_t)(Nn + 1) * 4);
  int*    cursor  = (int*)alloc((size_t)Nn * 4);
  int2*   epack   = (int2*)alloc((size_t)ET * 8);
  float*  ea_mean = (float*)alloc((size_t)FE * 4);
  float*  bn1s    = (float*)alloc(256 * 4);
  float*  bn1q    = (float*)alloc(256 * 4);
  float*  bn2s    = (float*)alloc(128 * 4);
  float*  bn2q    = (float*)alloc(128 * 4);
  float2* bncoef  = (float2*)alloc(256 * 8);
  float*  xl3     = (float*)alloc((size_t)Nn * 4);
  float*  xr3     = (float*)alloc((size_t)Nn * 4);
  u16*    xlA     = (u16*)alloc((size_t)Nn * 256 * 2);   // xl1 / xl2 (bf16 internal)
  u16*    hB      = (u16*)alloc((size_t)Nn * 256 * 2);   // h1 / h2 (bf16 internal, pre-BN)
  // total ≈ 57 MB

  k_init<<<512, 256, 0, stream>>>(deg, cursor, ea_mean, bn1s, bn1q, bn2s, bn2q);
  k_deg_mean<<<(ET + 255) / 256, 256, 0, stream>>>(ei, ea, deg, ea_mean);
  k_scan<<<1, 1024, 0, stream>>>(deg, rowptr);
  k_scatter<<<(ET + 255) / 256, 256, 0, stream>>>(ei, rowptr, cursor, epack);

  // ---- layer 1 ----
  k_gemm_mfma<FIN, HC1, float, false><<<dim3(HC1 / 64, (Nn + 63) / 64), 256, 0, stream>>>(
      x, W1, b1, xlA, nullptr, Nn);
  k_node_attn<HC1, C1, 2><<<2048, 256, 0, stream>>>(rowptr, epack, xlA, We1, att1,
                                                    ea, ea_mean, bo1, hB);
  k_bn_stats<HC1><<<256, 256, 0, stream>>>(hB, bn1s, bn1q);
  k_bn_coef<<<1, 256, 0, stream>>>(bn1s, bn1q, g1, bt1, bncoef, HC1);

  // ---- layer 2 (BN1+ELU fused into A-load) ----
  k_gemm_mfma<HC1, HC2, u16, true><<<dim3(HC2 / 64, (Nn + 63) / 64), 256, 0, stream>>>(
      hB, W2, b2, xlA, bncoef, Nn);
  k_node_attn<HC2, C2, 1><<<2048, 256, 0, stream>>>(rowptr, epack, xlA, We2, att2,
                                                    ea, ea_mean, bo2, hB);
  k_bn_stats<HC2><<<256, 256, 0, stream>>>(hB, bn2s, bn2q);
  k_bn_coef<<<1, 256, 0, stream>>>(bn2s, bn2q, g2, bt2, bncoef, HC2);

  // ---- layer 3 (BN2+ELU fused into h2 load) ----
  k_gemv3<<<(Nn + 3) / 4, 256, 0, stream>>>(hB, bncoef, W3l, b3l, W3r, b3r, xl3, xr3);
  k_final3<<<(Nn + 3) / 4, 256, 0, stream>>>(rowptr, epack, xl3, xr3, We3, att3,
                                             ea, ea_mean, bo3, out);
}